// Round 2
// baseline (211.796 us; speedup 1.0000x reference)
//
#include <hip/hip_runtime.h>
#include <math.h>

// Problem constants (fixed by the reference)
#define BATCH 2
#define NQ    300
#define NC    80
#define NFLAT (NQ * NC)     // 24000 per batch
#define TOPK  300
#define HM    128           // mask H=W
#define OUTS  480           // output H=W
#define NBKT  4096          // histogram buckets (top 12 bits of mapped float)
#define CAP   4096          // candidate capacity

#define INVSCALE (128.0 / 480.0)   // source-step per output pixel

// order-preserving map: float bits -> uint32 (monotone in float value)
__device__ __forceinline__ unsigned mapf(float x) {
    unsigned u = __float_as_uint(x);
    return (u & 0x80000000u) ? ~u : (u | 0x80000000u);
}

// ---------------------------------------------------------------------------
// Kernel 1: top-k selection + scores/labels/boxes, one block per batch sample
// ---------------------------------------------------------------------------
__global__ __launch_bounds__(1024) void topk_kernel(
    const float* __restrict__ logits,   // [B,Q,C]
    const float* __restrict__ boxes,    // [B,Q,4] cxcywh
    const float* __restrict__ osize,    // [B,2]
    float* __restrict__ out,            // header region of d_out
    int* __restrict__ qidx)             // [B*K] scratch (ws)
{
    __shared__ unsigned hist[NBKT];
    __shared__ unsigned long long cand[CAP];
    __shared__ unsigned part[1024];
    __shared__ unsigned sh_T;
    __shared__ unsigned sh_cnt;

    const int b = blockIdx.x;
    const int tid = threadIdx.x;
    const float* lg = logits + (size_t)b * NFLAT;

    // histogram of top 12 bits
    for (int i = tid; i < NBKT; i += 1024) hist[i] = 0;
    if (tid == 0) sh_cnt = 0;
    __syncthreads();
    for (int i = tid; i < NFLAT; i += 1024)
        atomicAdd(&hist[mapf(lg[i]) >> 20], 1u);
    __syncthreads();

    // two-level suffix scan to find threshold bucket T:
    // cnt(bucket > T) < K <= cnt(bucket >= T)
    part[tid] = hist[4 * tid] + hist[4 * tid + 1] + hist[4 * tid + 2] + hist[4 * tid + 3];
    __syncthreads();
    if (tid == 0) {
        unsigned acc = 0, T = 0;
        for (int g = 1023; g >= 0; --g) {
            if (acc + part[g] >= (unsigned)TOPK) {
                for (int bk = 4 * g + 3; bk >= 4 * g; --bk) {
                    if (acc + hist[bk] >= (unsigned)TOPK) { T = (unsigned)bk; break; }
                    acc += hist[bk];
                }
                break;
            }
            acc += part[g];
        }
        sh_T = T;
    }
    __syncthreads();
    const unsigned T = sh_T;

    // collect candidates (bucket >= T) as 64-bit keys: score desc, index asc
    for (int i = tid; i < NFLAT; i += 1024) {
        unsigned m = mapf(lg[i]);
        if ((m >> 20) >= T) {
            unsigned pos = atomicAdd(&sh_cnt, 1u);
            if (pos < CAP)
                cand[pos] = ((unsigned long long)m << 32) | (unsigned long long)(0xFFFFFFFFu - (unsigned)i);
        }
    }
    __syncthreads();
    unsigned cnt = sh_cnt; if (cnt > CAP) cnt = CAP;
    unsigned npow = 2; while (npow < cnt) npow <<= 1;
    for (unsigned i = cnt + tid; i < npow; i += 1024) cand[i] = 0ull;
    __syncthreads();

    // bitonic sort ascending (largest keys end up at the back)
    for (unsigned k = 2; k <= npow; k <<= 1) {
        for (unsigned j = k >> 1; j > 0; j >>= 1) {
            for (unsigned i = tid; i < npow; i += 1024) {
                unsigned ixj = i ^ j;
                if (ixj > i) {
                    unsigned long long a = cand[i], c2 = cand[ixj];
                    bool up = ((i & k) == 0);
                    if (up ? (a > c2) : (a < c2)) { cand[i] = c2; cand[ixj] = a; }
                }
            }
            __syncthreads();
        }
    }

    // emit top-K
    if (tid < TOPK) {
        unsigned long long key = cand[npow - 1 - (unsigned)tid];
        unsigned idx = 0xFFFFFFFFu - (unsigned)(key & 0xFFFFFFFFull);
        int q = (int)(idx / NC);
        int c = (int)(idx % NC);
        double x = (double)lg[idx];
        double score = 1.0 / (1.0 + exp(-x));

        out[b * TOPK + tid] = (float)score;                       // top_scores
        out[BATCH * TOPK + b * TOPK + tid] = (float)c;            // top_labels

        const float* bx = boxes + ((size_t)(b * NQ + q)) * 4;
        double cx = (double)bx[0], cy = (double)bx[1];
        double w  = (double)bx[2], h  = (double)bx[3];
        double s0 = (double)osize[b * 2 + 0];
        double s1 = (double)osize[b * 2 + 1];
        float* ob = out + 2 * BATCH * TOPK + ((size_t)(b * TOPK + tid)) * 4;
        ob[0] = (float)((cx - 0.5 * w) * s0);
        ob[1] = (float)((cy - 0.5 * h) * s1);
        ob[2] = (float)((cx + 0.5 * w) * s0);
        ob[3] = (float)((cy + 0.5 * h) * s1);

        qidx[b * TOPK + tid] = q;
    }
}

// ---------------------------------------------------------------------------
// Kernel 2: gather masks, sigmoid, bilinear 128->480, threshold.
// 3000 units = 600 masks x 5 slices of 96 output rows. 512 persistent blocks.
// ---------------------------------------------------------------------------
#define NUNITS   (BATCH * TOPK * 5)
#define MBLOCKS  512
#define ROWS_PER_SLICE 96
#define QUADS_PER_ROW  (OUTS / 4)   // 120
#define QUADS_PER_SLICE (ROWS_PER_SLICE * QUADS_PER_ROW)  // 11520

__global__ __launch_bounds__(1024) void mask_kernel(
    const float* __restrict__ masks,   // [B,Q,128,128]
    const int* __restrict__ qidx,      // [B*K]
    float* __restrict__ outm)          // d_out + 3600, [B*K,480,480]
{
    __shared__ double smd[32 * HM];    // sigmoid of <=28 source rows (double), 32KB
    const int tid = threadIdx.x;

    for (int u = blockIdx.x; u < NUNITS; u += MBLOCKS) {
        const int mask_id = u / 5;
        const int slice   = u % 5;
        const int b = mask_id / TOPK;
        const int q = qidx[mask_id];
        const int ys = slice * ROWS_PER_SLICE;

        // source row range for this slice
        double s_first = ((double)ys + 0.5) * INVSCALE - 0.5;
        double s_last  = ((double)(ys + ROWS_PER_SLICE - 1) + 0.5) * INVSCALE - 0.5;
        int r_lo = (int)floor(s_first); if (r_lo < 0) r_lo = 0;
        int r_hi = (int)floor(s_last) + 1; if (r_hi > HM - 1) r_hi = HM - 1;
        const int cnt = r_hi - r_lo + 1;   // <= 28

        __syncthreads();   // protect smd from previous unit's readers

        // stage rows [r_lo, r_hi] with double-precision sigmoid
        const float4* s4 = (const float4*)(masks
                          + ((size_t)(b * NQ + q)) * (HM * HM)
                          + (size_t)r_lo * HM);
        const int n4 = cnt * (HM / 4);
        for (int i = tid; i < n4; i += 1024) {
            float4 v = s4[i];
            smd[i * 4 + 0] = 1.0 / (1.0 + exp(-(double)v.x));
            smd[i * 4 + 1] = 1.0 / (1.0 + exp(-(double)v.y));
            smd[i * 4 + 2] = 1.0 / (1.0 + exp(-(double)v.z));
            smd[i * 4 + 3] = 1.0 / (1.0 + exp(-(double)v.w));
        }
        __syncthreads();

        float* outp = outm + (size_t)mask_id * (OUTS * OUTS);

        for (int t = tid; t < QUADS_PER_SLICE; t += 1024) {
            const int yy = t / QUADS_PER_ROW;
            const int qd = t % QUADS_PER_ROW;
            const int y = ys + yy;
            const int x0 = qd * 4;

            // y weights (triangle kernel w/ edge renormalization == clamp)
            double sy = ((double)y + 0.5) * INVSCALE - 0.5;
            int jy = (int)floor(sy);
            double fy;
            if (jy < 0)            { jy = 0;      fy = 0.0; }
            else if (jy >= HM - 1) { jy = HM - 1; fy = 0.0; }
            else                   { fy = sy - (double)jy; }
            const double* r0 = smd + (size_t)(jy - r_lo) * HM;
            int jy1 = jy + 1; if (jy1 > HM - 1) jy1 = HM - 1;
            const double* r1 = smd + (size_t)(jy1 - r_lo) * HM;
            const double wy1 = fy, wy0 = 1.0 - fy;

            // the 4 output pixels span at most 3 source columns
            double sx0 = ((double)x0 + 0.5) * INVSCALE - 0.5;
            int c0 = (int)floor(sx0); if (c0 < 0) c0 = 0;
            const int c1 = c0 + 1;
            int c2 = c0 + 2; if (c2 > HM - 1) c2 = HM - 1;

            const double t0 = wy0 * r0[c0] + wy1 * r1[c0];
            const double t1 = wy0 * r0[c1] + wy1 * r1[c1];
            const double t2 = wy0 * r0[c2] + wy1 * r1[c2];

            float4 res;
            float* rp = (float*)&res;
            #pragma unroll
            for (int j = 0; j < 4; ++j) {
                double sx = ((double)(x0 + j) + 0.5) * INVSCALE - 0.5;
                int jx = (int)floor(sx);
                double fx;
                if (jx < 0)            { jx = 0;      fx = 0.0; }
                else if (jx >= HM - 1) { jx = HM - 1; fx = 0.0; }
                else                   { fx = sx - (double)jx; }
                const int a = jx - c0;           // 0 or 1
                const double ta = a ? t1 : t0;
                const double tb = a ? t2 : t1;
                const double val = (1.0 - fx) * ta + fx * tb;
                rp[j] = (val > 0.5) ? 1.0f : 0.0f;
            }
            *((float4*)(outp + (size_t)y * OUTS + x0)) = res;
        }
    }
}

// ---------------------------------------------------------------------------
extern "C" void kernel_launch(void* const* d_in, const int* in_sizes, int n_in,
                              void* d_out, int out_size, void* d_ws, size_t ws_size,
                              hipStream_t stream) {
    const float* logits = (const float*)d_in[0];   // [2,300,80]
    const float* boxes  = (const float*)d_in[1];   // [2,300,4]
    const float* masks  = (const float*)d_in[2];   // [2,300,128,128]
    const float* osize  = (const float*)d_in[3];   // [2,2]
    float* out = (float*)d_out;
    int* qidx = (int*)d_ws;                        // 600 ints

    topk_kernel<<<BATCH, 1024, 0, stream>>>(logits, boxes, osize, out, qidx);

    // masks start after scores(600) + labels(600) + boxes(2400) = 3600 floats
    mask_kernel<<<MBLOCKS, 1024, 0, stream>>>(masks, qidx, out + 3600);
}

// Round 4
// 149.041 us; speedup vs baseline: 1.4211x; 1.4211x over previous
//
#include <hip/hip_runtime.h>
#include <math.h>

// Problem constants (fixed by the reference)
#define BATCH 2
#define NQ    300
#define NC    80
#define NFLAT (NQ * NC)     // 24000 per batch
#define TOPK  300
#define HM    128           // mask H=W
#define OUTS  480           // output H=W
#define NBKT  4096          // histogram buckets (top 12 bits of mapped float)
#define CAP   4096          // candidate capacity

#define INVSCALE (128.0 / 480.0)   // source-step per output pixel

typedef float v4f __attribute__((ext_vector_type(4)));

// order-preserving map: float bits -> uint32 (monotone in float value)
__device__ __forceinline__ unsigned mapf(float x) {
    unsigned u = __float_as_uint(x);
    return (u & 0x80000000u) ? ~u : (u | 0x80000000u);
}

// ---------------------------------------------------------------------------
// Kernel 1: top-k selection + scores/labels/boxes, one block per batch sample.
// Histogram select -> candidate collect -> rank-select (no serial scan/sort).
// ---------------------------------------------------------------------------
__global__ __launch_bounds__(1024) void topk_kernel(
    const float* __restrict__ logits,   // [B,Q,C]
    const float* __restrict__ boxes,    // [B,Q,4] cxcywh
    const float* __restrict__ osize,    // [B,2]
    float* __restrict__ out,            // header region of d_out
    int* __restrict__ qidx)             // [B*K] scratch (ws)
{
    __shared__ unsigned hist[NBKT];              // 16 KB
    __shared__ unsigned long long cand[CAP];     // 32 KB
    __shared__ unsigned psum[1024];              // 4 KB
    __shared__ unsigned sh_T;
    __shared__ unsigned sh_cnt;

    const int b = blockIdx.x;
    const int tid = threadIdx.x;
    const float* lg = logits + (size_t)b * NFLAT;

    // histogram of top 12 bits of the mapped float
    for (int i = tid; i < NBKT; i += 1024) hist[i] = 0;
    if (tid == 0) sh_cnt = 0;
    __syncthreads();
    for (int i = tid; i < NFLAT; i += 1024)
        atomicAdd(&hist[mapf(lg[i]) >> 20], 1u);
    __syncthreads();

    // parallel suffix scan over 1024 groups of 4 buckets
    unsigned gsum = hist[4 * tid] + hist[4 * tid + 1] + hist[4 * tid + 2] + hist[4 * tid + 3];
    psum[tid] = gsum;
    __syncthreads();
    for (unsigned off = 1; off < 1024; off <<= 1) {
        unsigned v = (tid + off < 1024) ? psum[tid + off] : 0u;
        __syncthreads();
        psum[tid] += v;
        __syncthreads();
    }
    // psum[t] = count of elements with bucket >= 4t (non-increasing in t).
    // the unique t where psum[t] >= K > psum[t+1] owns the threshold bucket.
    {
        unsigned nxt = (tid == 1023) ? 0u : psum[tid + 1];
        if (psum[tid] >= (unsigned)TOPK && nxt < (unsigned)TOPK) {
            unsigned acc = nxt, T = 4u * (unsigned)tid;
            for (int bk = 4 * tid + 3; bk >= 4 * tid; --bk) {
                if (acc + hist[bk] >= (unsigned)TOPK) { T = (unsigned)bk; break; }
                acc += hist[bk];
            }
            sh_T = T;
        }
    }
    __syncthreads();
    const unsigned T = sh_T;

    // collect candidates (bucket >= T) as 64-bit keys: score desc, index asc
    for (int i = tid; i < NFLAT; i += 1024) {
        unsigned m = mapf(lg[i]);
        if ((m >> 20) >= T) {
            unsigned pos = atomicAdd(&sh_cnt, 1u);
            if (pos < CAP)
                cand[pos] = ((unsigned long long)m << 32)
                          | (unsigned long long)(0xFFFFFFFFu - (unsigned)i);
        }
    }
    __syncthreads();
    const unsigned cnt = (sh_cnt > CAP) ? CAP : sh_cnt;

    // rank-select: rank = #{keys greater than mine}; ranks are unique.
    for (unsigned t = tid; t < cnt; t += 1024) {
        const unsigned long long my = cand[t];
        unsigned rank = 0;
        for (unsigned j = 0; j < cnt; ++j) rank += (cand[j] > my) ? 1u : 0u;
        if (rank < (unsigned)TOPK) {
            unsigned idx = 0xFFFFFFFFu - (unsigned)(my & 0xFFFFFFFFull);
            int q = (int)(idx / NC);
            int c = (int)(idx % NC);
            double x = (double)lg[idx];
            double score = 1.0 / (1.0 + exp(-x));

            out[b * TOPK + rank] = (float)score;                   // top_scores
            out[BATCH * TOPK + b * TOPK + rank] = (float)c;        // top_labels

            const float* bx = boxes + ((size_t)(b * NQ + q)) * 4;
            double cx = (double)bx[0], cy = (double)bx[1];
            double w  = (double)bx[2], h  = (double)bx[3];
            double s0 = (double)osize[b * 2 + 0];
            double s1 = (double)osize[b * 2 + 1];
            float* ob = out + 2 * BATCH * TOPK + ((size_t)(b * TOPK + rank)) * 4;
            ob[0] = (float)((cx - 0.5 * w) * s0);
            ob[1] = (float)((cy - 0.5 * h) * s1);
            ob[2] = (float)((cx + 0.5 * w) * s0);
            ob[3] = (float)((cy + 0.5 * h) * s1);

            qidx[b * TOPK + rank] = q;
        }
    }
}

// ---------------------------------------------------------------------------
// Kernel 2: gather masks, sigmoid, bilinear 128->480, threshold. All f32.
// 3000 units = 600 masks x 5 slices of 96 output rows. 512 persistent blocks.
// ---------------------------------------------------------------------------
#define SLICES   5
#define OROWS    96
#define NUNITS   (BATCH * TOPK * SLICES)
#define MBLOCKS  512

__global__ __launch_bounds__(1024) void mask_kernel(
    const float* __restrict__ masks,   // [B,Q,128,128]
    const int* __restrict__ qidx,      // [B*K]
    float* __restrict__ outm)          // d_out + 3600, [B*K,480,480]
{
    __shared__ float sig[28 * HM];     // sigmoid of <=28 source rows, 14 KB
    __shared__ int   jt[OUTS];         // clamped floor index per output coord
    __shared__ float ft[OUTS];         // clamped frac weight per output coord

    const int tid = threadIdx.x;

    // index/weight table (square problem: same table serves rows and cols)
    for (int i = tid; i < OUTS; i += 1024) {
        double s = ((double)i + 0.5) * INVSCALE - 0.5;
        int j = (int)floor(s);
        if (j < 0) j = 0;
        if (j > HM - 2) j = HM - 2;
        double f = s - (double)j;
        if (f < 0.0) f = 0.0;
        if (f > 1.0) f = 1.0;
        jt[i] = j;
        ft[i] = (float)f;
    }

    // per-thread column geometry (fixed: depends only on tid)
    const int yy0 = tid / 120;         // 0..7 (for tid < 960)
    const int qd  = tid % 120;
    const int x0  = qd * 4;
    int   c0 = 0, ar[4];
    float fxr[4];
    #pragma unroll
    for (int j = 0; j < 4; ++j) {
        double sx = ((double)(x0 + j) + 0.5) * INVSCALE - 0.5;
        int jx = (int)floor(sx);
        if (jx < 0) jx = 0;
        if (jx > HM - 2) jx = HM - 2;
        double f = sx - (double)jx;
        if (f < 0.0) f = 0.0;
        if (f > 1.0) f = 1.0;
        if (j == 0) c0 = jx;
        ar[j]  = jx - c0;              // 0 or 1
        fxr[j] = (float)f;
    }
    const int c1 = c0 + 1;
    const int c2 = (c0 + 2 > HM - 1) ? (HM - 1) : (c0 + 2);   // value unused when clamped
    __syncthreads();

    for (int u = blockIdx.x; u < NUNITS; u += MBLOCKS) {
        const int mask_id = u / SLICES;
        const int slice   = u % SLICES;
        const int b = mask_id / TOPK;
        const int q = qidx[mask_id];
        const int ys = slice * OROWS;
        const int r_lo = jt[ys];
        const int r_hi = jt[ys + OROWS - 1] + 1;   // <= 127
        const int cnt  = r_hi - r_lo + 1;          // <= 28

        __syncthreads();   // previous unit's readers are done with sig

        // stage source rows [r_lo, r_hi] as f32 sigmoid (one 16B load/thread)
        const v4f* s4 = (const v4f*)(masks
                          + ((size_t)(b * NQ + q)) * (HM * HM)
                          + (size_t)r_lo * HM);
        const int n4 = cnt * (HM / 4);             // <= 896
        if (tid < n4) {
            v4f v = s4[tid];
            float* dst = sig + tid * 4;
            dst[0] = 1.0f / (1.0f + __expf(-v.x));
            dst[1] = 1.0f / (1.0f + __expf(-v.y));
            dst[2] = 1.0f / (1.0f + __expf(-v.z));
            dst[3] = 1.0f / (1.0f + __expf(-v.w));
        }
        __syncthreads();

        if (tid < 960) {
            float* outp = outm + (size_t)mask_id * (OUTS * OUTS)
                               + (size_t)(ys + yy0) * OUTS + x0;
            #pragma unroll
            for (int it = 0; it < 12; ++it) {
                const int y  = ys + yy0 + it * 8;
                const int jy = jt[y] - r_lo;
                const float wy1 = ft[y];
                const float wy0 = 1.0f - wy1;
                const float* r0 = sig + jy * HM;
                const float* r1 = r0 + HM;

                const float t0 = wy0 * r0[c0] + wy1 * r1[c0];
                const float t1 = wy0 * r0[c1] + wy1 * r1[c1];
                const float t2 = wy0 * r0[c2] + wy1 * r1[c2];

                v4f res;
                #pragma unroll
                for (int j = 0; j < 4; ++j) {
                    const float ta = ar[j] ? t1 : t0;
                    const float tb = ar[j] ? t2 : t1;
                    const float val = ta + fxr[j] * (tb - ta);
                    res[j] = (val > 0.5f) ? 1.0f : 0.0f;
                }
                __builtin_nontemporal_store(res, (v4f*)(outp + (size_t)(it * 8) * OUTS));
            }
        }
    }
}

// ---------------------------------------------------------------------------
extern "C" void kernel_launch(void* const* d_in, const int* in_sizes, int n_in,
                              void* d_out, int out_size, void* d_ws, size_t ws_size,
                              hipStream_t stream) {
    const float* logits = (const float*)d_in[0];   // [2,300,80]
    const float* boxes  = (const float*)d_in[1];   // [2,300,4]
    const float* masks  = (const float*)d_in[2];   // [2,300,128,128]
    const float* osize  = (const float*)d_in[3];   // [2,2]
    float* out = (float*)d_out;
    int* qidx = (int*)d_ws;                        // 600 ints

    topk_kernel<<<BATCH, 1024, 0, stream>>>(logits, boxes, osize, out, qidx);

    // masks start after scores(600) + labels(600) + boxes(2400) = 3600 floats
    mask_kernel<<<MBLOCKS, 1024, 0, stream>>>(masks, qidx, out + 3600);
}